// Round 6
// baseline (240.610 us; speedup 1.0000x reference)
//
#include <hip/hip_runtime.h>
#include <hip/hip_bf16.h>
#include <stdint.h>

#define BATCH 2
#define SEQ 2048
#define DMODEL 1024
#define NHEADS 16
#define HDIM 64
#define MROWS (BATCH*SEQ)   /* 4096 */
#define N3 (3*DMODEL)       /* 3072 */
#define NSLOT 80            /* chunk-slots per bh: sum over qt of ceil((qt+1)/8) */

typedef __attribute__((ext_vector_type(8))) __bf16 bf16x8;
typedef __attribute__((ext_vector_type(4))) float f32x4;

__device__ __forceinline__ ushort f2b(float f) {
  uint32_t u = __builtin_bit_cast(uint32_t, f);
  uint32_t r = (u + 0x7FFFu + ((u >> 16) & 1u)) >> 16;
  return (ushort)r;
}
__device__ __forceinline__ float b2f(ushort h) {
  return __builtin_bit_cast(float, (uint32_t)h << 16);
}
__device__ __forceinline__ float exp2_hw(float x) {
  float r;
  asm("v_exp_f32 %0, %1" : "=v"(r) : "v"(x));
  return r;
}

/* ---------------- f32 -> bf16 convert, 4 elems/thread ---------------- */
__global__ void f2b_kernel(const float* __restrict__ in, ushort* __restrict__ out, int n4) {
  int i = blockIdx.x * blockDim.x + threadIdx.x;
  if (i < n4) {
    float4 v = ((const float4*)in)[i];
    ushort4 o;
    o.x = f2b(v.x); o.y = f2b(v.y); o.z = f2b(v.z); o.w = f2b(v.w);
    ((ushort4*)out)[i] = o;
  }
}

/* ---------------- RoPE cos/sin table: [SEQ][32] each ---------------- */
__global__ void rope_table_kernel(float* __restrict__ cs, float* __restrict__ sn) {
  int idx = blockIdx.x * blockDim.x + threadIdx.x;
  int i = idx & 31;
  int l = idx >> 5;
  float inv = powf(10000.0f, -((float)i) / 32.0f);
  float ang = (float)l * inv;
  cs[idx] = cosf(ang);
  sn[idx] = sinf(ang);
}

/* ---------------- NT GEMM: C[M,N] = A[M,K] * Bw[N,K]^T  (m97 structure) ---------------- */
template<int OUTF>
__global__ __launch_bounds__(256)
void gemm_bt(const ushort* __restrict__ A, const ushort* __restrict__ Bw,
             void* __restrict__ Cv, int M, int N, int K) {
  __shared__ __align__(16) ushort As[128*32];
  __shared__ __align__(16) ushort Bs[128*32];
  const int tid  = threadIdx.x;
  const int wid  = tid >> 6;
  const int lane = tid & 63;
  const int wr   = wid >> 1, wc = wid & 1;
  const int l16  = lane & 15, lhi = lane >> 4;
  const int nb   = N >> 7;
  const int brow = (blockIdx.x / nb) << 7;
  const int bcol = (blockIdx.x % nb) << 7;

  f32x4 acc[4][4] = {};

  for (int k0 = 0; k0 < K; k0 += 32) {
    __syncthreads();
#pragma unroll
    for (int it = 0; it < 2; ++it) {
      const int cb    = (wid * 2 + it) * 64;
      const int chunk = cb + lane;
      const int r     = chunk >> 2;
      const int c8    = chunk & 3;
      const ushort* ga = A  + (size_t)(brow + r) * K + k0 + c8 * 8;
      const ushort* gb = Bw + (size_t)(bcol + r) * K + k0 + c8 * 8;
      __builtin_amdgcn_global_load_lds(
          (const __attribute__((address_space(1))) void*)ga,
          (__attribute__((address_space(3))) void*)(As + cb * 8), 16, 0, 0);
      __builtin_amdgcn_global_load_lds(
          (const __attribute__((address_space(1))) void*)gb,
          (__attribute__((address_space(3))) void*)(Bs + cb * 8), 16, 0, 0);
    }
    __syncthreads();

    bf16x8 af[4], bfr[4];
#pragma unroll
    for (int m = 0; m < 4; ++m)
      af[m] = *(const bf16x8*)(As + (wr*64 + m*16 + l16)*32 + lhi*8);
#pragma unroll
    for (int n = 0; n < 4; ++n)
      bfr[n] = *(const bf16x8*)(Bs + (wc*64 + n*16 + l16)*32 + lhi*8);
#pragma unroll
    for (int m = 0; m < 4; ++m)
#pragma unroll
      for (int n = 0; n < 4; ++n)
        acc[m][n] = __builtin_amdgcn_mfma_f32_16x16x32_bf16(af[m], bfr[n], acc[m][n], 0, 0, 0);
  }

#pragma unroll
  for (int m = 0; m < 4; ++m)
#pragma unroll
    for (int n = 0; n < 4; ++n)
#pragma unroll
      for (int r = 0; r < 4; ++r) {
        const int row = brow + wr*64 + m*16 + lhi*4 + r;
        const int col = bcol + wc*64 + n*16 + l16;
        if (OUTF) ((float*)Cv)[(size_t)row * N + col] = acc[m][n][r];
        else      ((ushort*)Cv)[(size_t)row * N + col] = f2b(acc[m][n][r]);
      }
}

/* ---------------- RoPE: kqv(bf16) -> Qb (pre-scaled by 0.125*log2e), Kb (b,h,L,64) ---------------- */
__global__ void rope_kernel(const ushort* __restrict__ kqv,
                            const float* __restrict__ cs, const float* __restrict__ sn,
                            ushort* __restrict__ qb, ushort* __restrict__ kb) {
  const float SC = 0.18033688011112042f;  /* 0.125 * log2(e): folds 1/sqrt(d) and exp->exp2 */
  int idx = blockIdx.x * blockDim.x + threadIdx.x;
  int i  = idx & 31;
  int h  = (idx >> 5) & 15;
  int bl = idx >> 9;
  int l  = bl & (SEQ - 1);
  int b  = bl >> 11;
  float c = cs[l * 32 + i];
  float s = sn[l * 32 + i];
  size_t base = (size_t)bl * N3 + h * HDIM + 2 * i;
  uint32_t kp = *(const uint32_t*)(kqv + base);
  uint32_t qp = *(const uint32_t*)(kqv + base + DMODEL);
  float k1 = b2f((ushort)(kp & 0xffff)), k2 = b2f((ushort)(kp >> 16));
  float q1 = b2f((ushort)(qp & 0xffff)), q2 = b2f((ushort)(qp >> 16));
  float kr1 = k1 * c - k2 * s, kr2 = k1 * s + k2 * c;
  float qr1 = (q1 * c - q2 * s) * SC, qr2 = (q1 * s + q2 * c) * SC;
  size_t ob = ((size_t)(b * NHEADS + h) * SEQ + l) * HDIM + 2 * i;
  *(uint32_t*)(kb + ob) = (uint32_t)f2b(kr1) | ((uint32_t)f2b(kr2) << 16);
  *(uint32_t*)(qb + ob) = (uint32_t)f2b(qr1) | ((uint32_t)f2b(qr2) << 16);
}

/* ---------------- V transpose: kqv cols [2048,3072) -> Vt (b,h,64,L) bf16 ---------------- */
__global__ void vtrans_kernel(const ushort* __restrict__ kqv, ushort* __restrict__ vt) {
  __shared__ ushort tile[64][65];
  int bid = blockIdx.x;
  int lt = bid & 31, bh = bid >> 5;
  int b = bh >> 4, h = bh & 15;
  int tid = threadIdx.x;
  int r = tid >> 2, cq = tid & 3;
  size_t gbase = ((size_t)(b * SEQ + lt * 64 + r)) * N3 + 2 * DMODEL + h * HDIM + cq * 16;
#pragma unroll
  for (int j = 0; j < 16; ++j) tile[r][cq * 16 + j] = kqv[gbase + j];
  __syncthreads();
  int d = tid >> 2;
  size_t obase = ((size_t)(bh * HDIM + d)) * SEQ + lt * 64 + cq * 16;
#pragma unroll
  for (int j = 0; j < 16; ++j) vt[obase + j] = tile[cq * 16 + j][d];
}

/* ---------------- Flash attention partials: swapped-QK 16x16, split-KV ----------------
   Outer structure = R2/R3 (verified): block=(bh, slot), slot -> (qt, 8-kt chunk),
   grid 2560 uniform, partials (m,l,unnorm O) + merge kernel.
   Inner loop (new): S^T = mfma(A=K, B=Q) -> lane holds S[q=r0+l16][kv=kt*64+n*16+lhi*4+r].
   Uses ONLY harness-verified 16x16x32 facts: D[m=lhi*4+r][n=l16], arg0->M arg1->N,
   equal A/B operand k-maps (cancellation). Row softmax = in-register tree + 2 shfl_xor
   (lanes sharing l16) -- replaces R3's 32 serial shuffles/iter. P bounced via verified
   LDS path; PV + partial store verbatim R3. */
__global__ __launch_bounds__(256, 4)
void attn_part_kernel(const ushort* __restrict__ qb, const ushort* __restrict__ kb,
                      const ushort* __restrict__ vt,
                      ushort* __restrict__ po, float* __restrict__ pm, float* __restrict__ pl) {
  __shared__ __align__(16) ushort plds[4][16 * 64];
  int bid = blockIdx.x;
  int bh = bid & 31;
  int slot = bid >> 5;
  int band = (slot < 8) ? 0 : (slot < 24) ? 1 : (slot < 48) ? 2 : 3;
  const int offb0 = (band == 0) ? 0 : (band == 1) ? 8 : (band == 2) ? 24 : 48;
  int s0i = slot - offb0;
  int qt = band * 8 + s0i / (band + 1);
  int c  = s0i % (band + 1);
  int kt0   = c * 8;
  int ktend = min(kt0 + 8, qt + 1);

  int wid = threadIdx.x >> 6, lane = threadIdx.x & 63;
  int l16 = lane & 15, lhi = lane >> 4;
  int r0 = qt * 64 + wid * 16;       /* wave's q-block; this lane's softmax q = r0 + l16 */

  const ushort* Q  = qb + (size_t)bh * SEQ * HDIM;
  const ushort* Kp = kb + (size_t)bh * SEQ * HDIM;
  const ushort* Vp = vt + (size_t)bh * HDIM * SEQ;

  bf16x8 qf[2];
#pragma unroll
  for (int kc = 0; kc < 2; ++kc)
    qf[kc] = *(const bf16x8*)(Q + (size_t)(r0 + l16) * HDIM + kc * 32 + lhi * 8);

  float mq = -3.0e38f, lsq = 0.0f;   /* state for q = r0 + l16 */
  f32x4 o[4] = {};                   /* o[f][r] = O[q=r0+lhi*4+r][d=f*16+l16], unnormalized */

  char* pbase = (char*)&plds[wid][0];
  const int swz = (l16 & 7) << 4;    /* row-based XOR swizzle, consistent write/read */

  for (int kt = kt0; kt < ktend; ++kt) {
    /* S^T = K * Q^T: s[n][r] = S[q=r0+l16][kv=kt*64+n*16+lhi*4+r] */
    f32x4 s[4];
#pragma unroll
    for (int n = 0; n < 4; ++n) {
      bf16x8 kf0 = *(const bf16x8*)(Kp + (size_t)(kt*64 + n*16 + l16) * HDIM + 0*32 + lhi*8);
      bf16x8 kf1 = *(const bf16x8*)(Kp + (size_t)(kt*64 + n*16 + l16) * HDIM + 1*32 + lhi*8);
      f32x4 z = 0.0f;
      z = __builtin_amdgcn_mfma_f32_16x16x32_bf16(kf0, qf[0], z, 0, 0, 0);
      z = __builtin_amdgcn_mfma_f32_16x16x32_bf16(kf1, qf[1], z, 0, 0, 0);
      s[n] = z;
    }

    /* causal mask on diagonal tile: kv > q */
    if (kt == qt) {
#pragma unroll
      for (int n = 0; n < 4; ++n)
#pragma unroll
        for (int r = 0; r < 4; ++r)
          if (kt*64 + n*16 + lhi*4 + r > r0 + l16) s[n][r] = -3.0e38f;
    }

    /* row max: tree over this lane's 16 kv + 2 shfl_xor across lanes sharing l16 */
    float t0 = fmaxf(fmaxf(s[0][0], s[0][1]), fmaxf(s[0][2], s[0][3]));
    float t1 = fmaxf(fmaxf(s[1][0], s[1][1]), fmaxf(s[1][2], s[1][3]));
    float t2 = fmaxf(fmaxf(s[2][0], s[2][1]), fmaxf(s[2][2], s[2][3]));
    float t3 = fmaxf(fmaxf(s[3][0], s[3][1]), fmaxf(s[3][2], s[3][3]));
    float pmx = fmaxf(fmaxf(t0, t1), fmaxf(t2, t3));
    pmx = fmaxf(pmx, __shfl_xor(pmx, 16));
    pmx = fmaxf(pmx, __shfl_xor(pmx, 32));

    /* rescale only when the running max grows (wave-uniform branch, exact) */
    if (!__all(pmx <= mq)) {
      float mn = fmaxf(mq, pmx);
      float alpha = exp2_hw(mq - mn);
      mq = mn;
      lsq *= alpha;
      float alphaT[4];
#pragma unroll
      for (int r = 0; r < 4; ++r)
        alphaT[r] = __shfl(alpha, lhi * 4 + r);   /* alpha for o's q = r0+lhi*4+r */
#pragma unroll
      for (int f = 0; f < 4; ++f)
#pragma unroll
        for (int r = 0; r < 4; ++r)
          o[f][r] *= alphaT[r];
    }

    /* p = exp2(s - m); sum via tree + 2 shfl_xor */
    float ps = 0.0f;
#pragma unroll
    for (int n = 0; n < 4; ++n)
#pragma unroll
      for (int r = 0; r < 4; ++r) {
        float p = exp2_hw(s[n][r] - mq);
        s[n][r] = p;
        ps += p;
      }
    ps += __shfl_xor(ps, 16);
    ps += __shfl_xor(ps, 32);
    lsq += ps;

    /* write P[q=l16][kv] to wave-private LDS (pairs of consecutive r = consecutive kv) */
#pragma unroll
    for (int n = 0; n < 4; ++n) {
      uint32_t w0 = (uint32_t)f2b(s[n][0]) | ((uint32_t)f2b(s[n][1]) << 16);
      uint32_t w1 = (uint32_t)f2b(s[n][2]) | ((uint32_t)f2b(s[n][3]) << 16);
      int kvloc = n*16 + lhi*4;
      *(uint32_t*)(pbase + ((l16*128 + kvloc*2) ^ swz))       = w0;
      *(uint32_t*)(pbase + ((l16*128 + (kvloc+2)*2) ^ swz))   = w1;
    }

    /* read A-frags (verified path: same assumed k-map as V B-frags -> cancels) */
    bf16x8 pa0 = *(const bf16x8*)(pbase + ((l16*128 + 0*64 + lhi*16) ^ swz));
    bf16x8 pa1 = *(const bf16x8*)(pbase + ((l16*128 + 1*64 + lhi*16) ^ swz));

    /* PV: verbatim R3 (verified) */
#pragma unroll
    for (int f = 0; f < 4; ++f) {
      bf16x8 vf0 = *(const bf16x8*)(Vp + (size_t)(f*16 + l16) * SEQ + kt*64 + 0*32 + lhi*8);
      bf16x8 vf1 = *(const bf16x8*)(Vp + (size_t)(f*16 + l16) * SEQ + kt*64 + 1*32 + lhi*8);
      o[f] = __builtin_amdgcn_mfma_f32_16x16x32_bf16(pa0, vf0, o[f], 0, 0, 0);
      o[f] = __builtin_amdgcn_mfma_f32_16x16x32_bf16(pa1, vf1, o[f], 0, 0, 0);
    }
  }

  /* store partials (same layout as R3; merge kernel unchanged except exp2f) */
  size_t pb = (size_t)bh * NSLOT + slot;
  if (lhi == 0) {
    pm[pb * 64 + wid * 16 + l16] = mq;
    pl[pb * 64 + wid * 16 + l16] = lsq;
  }
  int qlr = wid * 16 + lhi * 4;
#pragma unroll
  for (int r = 0; r < 4; ++r)
#pragma unroll
    for (int f = 0; f < 4; ++f)
      po[pb * 4096 + (size_t)(qlr + r) * 64 + f*16 + l16] = f2b(o[f][r]);
}

/* ---------------- Merge partials -> attn (b,L,h*d) bf16 ---------------- */
__global__ __launch_bounds__(256)
void attn_merge_kernel(const ushort* __restrict__ po, const float* __restrict__ pm,
                       const float* __restrict__ pl, ushort* __restrict__ attn) {
  int bid = blockIdx.x;            /* 1024: bh = bid&31, qt = bid>>5 */
  int bh = bid & 31, qt = bid >> 5;
  int band = qt >> 3;
  int nc = band + 1;
  int off = band * (band + 1) * 4 + (qt & 7) * (band + 1);
  size_t sbase = (size_t)bh * NSLOT + off;
  int t = threadIdx.x;
  int r = t >> 2, cg = t & 3;

  float mv[4], w[4];
  float M = -3.0e38f;
#pragma unroll
  for (int ci = 0; ci < 4; ++ci) {
    mv[ci] = (ci < nc) ? pm[(sbase + ci) * 64 + r] : -3.0e38f;
    M = fmaxf(M, mv[ci]);
  }
  float L = 0.0f;
#pragma unroll
  for (int ci = 0; ci < 4; ++ci) {
    w[ci] = (ci < nc) ? exp2f(mv[ci] - M) : 0.0f;
    if (ci < nc) L += w[ci] * pl[(sbase + ci) * 64 + r];
  }
  float acc[16] = {};
#pragma unroll
  for (int ci = 0; ci < 4; ++ci) {
    if (ci < nc) {
      const ushort* op = po + (sbase + ci) * 4096 + (size_t)r * 64 + cg * 16;
      uint4 v0 = *(const uint4*)op;
      uint4 v1 = *(const uint4*)(op + 8);
      const uint32_t uu[8] = {v0.x, v0.y, v0.z, v0.w, v1.x, v1.y, v1.z, v1.w};
#pragma unroll
      for (int j = 0; j < 8; ++j) {
        acc[2*j]   += w[ci] * b2f((ushort)(uu[j] & 0xffff));
        acc[2*j+1] += w[ci] * b2f((ushort)(uu[j] >> 16));
      }
    }
  }
  float invL = 1.0f / L;
  int b = bh >> 4, h = bh & 15;
  size_t ob = ((size_t)(b * SEQ + qt * 64 + r)) * DMODEL + h * 64 + cg * 16;
  uint32_t packed[8];
#pragma unroll
  for (int j = 0; j < 8; ++j)
    packed[j] = (uint32_t)f2b(acc[2*j] * invL) | ((uint32_t)f2b(acc[2*j+1] * invL) << 16);
  *(uint4*)(attn + ob)     = make_uint4(packed[0], packed[1], packed[2], packed[3]);
  *(uint4*)(attn + ob + 8) = make_uint4(packed[4], packed[5], packed[6], packed[7]);
}

extern "C" void kernel_launch(void* const* d_in, const int* in_sizes, int n_in,
                              void* d_out, int out_size, void* d_ws, size_t ws_size,
                              hipStream_t stream) {
  const float* x    = (const float*)d_in[0];
  const float* wkqv = (const float*)d_in[1];
  const float* wo   = (const float*)d_in[2];
  float* out = (float*)d_out;

  ushort* xb   = (ushort*)d_ws;                     /* 4096*1024 — reused as attn out */
  ushort* wkb  = xb  + (size_t)MROWS * DMODEL;      /* 3072*1024 */
  ushort* wob  = wkb + (size_t)N3 * DMODEL;         /* 1024*1024 */
  ushort* kqv  = wob + (size_t)DMODEL * DMODEL;     /* 4096*3072 — reused for partials */
  ushort* qb   = kqv + (size_t)MROWS * N3;          /* 4096*1024 */
  ushort* kb   = qb  + (size_t)MROWS * DMODEL;      /* 4096*1024 */
  ushort* vt   = kb  + (size_t)MROWS * DMODEL;      /* 4096*1024 */
  float*  cs   = (float*)(vt + (size_t)MROWS * DMODEL);
  float*  sn   = cs + SEQ * 32;
  ushort* attn = xb;  /* alias: xb dead after GEMM1 */

  /* partials alias kqv (dead after rope+vtrans) */
  ushort* po = kqv;
  float*  pmv = (float*)(kqv + (size_t)32 * NSLOT * 4096);
  float*  plv = pmv + (size_t)32 * NSLOT * 64;

  int nx = MROWS * DMODEL / 4, nw = N3 * DMODEL / 4, no = DMODEL * DMODEL / 4;
  f2b_kernel<<<nx / 256, 256, 0, stream>>>(x, xb, nx);
  f2b_kernel<<<nw / 256, 256, 0, stream>>>(wkqv, wkb, nw);
  f2b_kernel<<<no / 256, 256, 0, stream>>>(wo, wob, no);
  rope_table_kernel<<<SEQ * 32 / 256, 256, 0, stream>>>(cs, sn);

  gemm_bt<0><<<(MROWS/128) * (N3/128), 256, 0, stream>>>(xb, wkb, (void*)kqv, MROWS, N3, DMODEL);

  rope_kernel<<<(MROWS * NHEADS * 32) / 256, 256, 0, stream>>>(kqv, cs, sn, qb, kb);
  vtrans_kernel<<<BATCH * NHEADS * (SEQ / 64), 256, 0, stream>>>(kqv, vt);

  attn_part_kernel<<<32 * NSLOT, 256, 0, stream>>>(qb, kb, vt, po, pmv, plv);
  attn_merge_kernel<<<32 * 32, 256, 0, stream>>>(po, pmv, plv, attn);

  gemm_bt<1><<<(MROWS/128) * (DMODEL/128), 256, 0, stream>>>(attn, wob, (void*)out, MROWS, DMODEL, DMODEL);
}

// Round 7
// 144.066 us; speedup vs baseline: 1.6701x; 1.6701x over previous
//
#include <hip/hip_runtime.h>
#include <hip/hip_bf16.h>
#include <stdint.h>

#define BATCH 2
#define SEQ 2048
#define DMODEL 1024
#define NHEADS 16
#define HDIM 64
#define MROWS (BATCH*SEQ)   /* 4096 */
#define N3 (3*DMODEL)       /* 3072 */
#define NSLOT 80            /* chunk-slots per bh: sum over qt of ceil((qt+1)/8) */

typedef __attribute__((ext_vector_type(8))) __bf16 bf16x8;
typedef __attribute__((ext_vector_type(4))) float f32x4;

__device__ __forceinline__ ushort f2b(float f) {
  uint32_t u = __builtin_bit_cast(uint32_t, f);
  uint32_t r = (u + 0x7FFFu + ((u >> 16) & 1u)) >> 16;
  return (ushort)r;
}
__device__ __forceinline__ float b2f(ushort h) {
  return __builtin_bit_cast(float, (uint32_t)h << 16);
}
__device__ __forceinline__ float exp2_hw(float x) {
  float r;
  asm("v_exp_f32 %0, %1" : "=v"(r) : "v"(x));
  return r;
}

/* ---------------- f32 -> bf16 convert, 4 elems/thread ---------------- */
__global__ void f2b_kernel(const float* __restrict__ in, ushort* __restrict__ out, int n4) {
  int i = blockIdx.x * blockDim.x + threadIdx.x;
  if (i < n4) {
    float4 v = ((const float4*)in)[i];
    ushort4 o;
    o.x = f2b(v.x); o.y = f2b(v.y); o.z = f2b(v.z); o.w = f2b(v.w);
    ((ushort4*)out)[i] = o;
  }
}

/* ---------------- RoPE cos/sin table: [SEQ][32] each ---------------- */
__global__ void rope_table_kernel(float* __restrict__ cs, float* __restrict__ sn) {
  int idx = blockIdx.x * blockDim.x + threadIdx.x;
  int i = idx & 31;
  int l = idx >> 5;
  float inv = powf(10000.0f, -((float)i) / 32.0f);
  float ang = (float)l * inv;
  cs[idx] = cosf(ang);
  sn[idx] = sinf(ang);
}

/* ---------------- NT GEMM: C[M,N] = A[M,K] * Bw[N,K]^T  (m97 structure) ---------------- */
template<int OUTF>
__global__ __launch_bounds__(256)
void gemm_bt(const ushort* __restrict__ A, const ushort* __restrict__ Bw,
             void* __restrict__ Cv, int M, int N, int K) {
  __shared__ __align__(16) ushort As[128*32];
  __shared__ __align__(16) ushort Bs[128*32];
  const int tid  = threadIdx.x;
  const int wid  = tid >> 6;
  const int lane = tid & 63;
  const int wr   = wid >> 1, wc = wid & 1;
  const int l16  = lane & 15, lhi = lane >> 4;
  const int nb   = N >> 7;
  const int brow = (blockIdx.x / nb) << 7;
  const int bcol = (blockIdx.x % nb) << 7;

  f32x4 acc[4][4] = {};

  for (int k0 = 0; k0 < K; k0 += 32) {
    __syncthreads();
#pragma unroll
    for (int it = 0; it < 2; ++it) {
      const int cb    = (wid * 2 + it) * 64;
      const int chunk = cb + lane;
      const int r     = chunk >> 2;
      const int c8    = chunk & 3;
      const ushort* ga = A  + (size_t)(brow + r) * K + k0 + c8 * 8;
      const ushort* gb = Bw + (size_t)(bcol + r) * K + k0 + c8 * 8;
      __builtin_amdgcn_global_load_lds(
          (const __attribute__((address_space(1))) void*)ga,
          (__attribute__((address_space(3))) void*)(As + cb * 8), 16, 0, 0);
      __builtin_amdgcn_global_load_lds(
          (const __attribute__((address_space(1))) void*)gb,
          (__attribute__((address_space(3))) void*)(Bs + cb * 8), 16, 0, 0);
    }
    __syncthreads();

    bf16x8 af[4], bfr[4];
#pragma unroll
    for (int m = 0; m < 4; ++m)
      af[m] = *(const bf16x8*)(As + (wr*64 + m*16 + l16)*32 + lhi*8);
#pragma unroll
    for (int n = 0; n < 4; ++n)
      bfr[n] = *(const bf16x8*)(Bs + (wc*64 + n*16 + l16)*32 + lhi*8);
#pragma unroll
    for (int m = 0; m < 4; ++m)
#pragma unroll
      for (int n = 0; n < 4; ++n)
        acc[m][n] = __builtin_amdgcn_mfma_f32_16x16x32_bf16(af[m], bfr[n], acc[m][n], 0, 0, 0);
  }

#pragma unroll
  for (int m = 0; m < 4; ++m)
#pragma unroll
    for (int n = 0; n < 4; ++n)
#pragma unroll
      for (int r = 0; r < 4; ++r) {
        const int row = brow + wr*64 + m*16 + lhi*4 + r;
        const int col = bcol + wc*64 + n*16 + l16;
        if (OUTF) ((float*)Cv)[(size_t)row * N + col] = acc[m][n][r];
        else      ((ushort*)Cv)[(size_t)row * N + col] = f2b(acc[m][n][r]);
      }
}

/* ---------------- RoPE: kqv(bf16) -> Qb (pre-scaled by 0.125*log2e), Kb (b,h,L,64) ---------------- */
__global__ void rope_kernel(const ushort* __restrict__ kqv,
                            const float* __restrict__ cs, const float* __restrict__ sn,
                            ushort* __restrict__ qb, ushort* __restrict__ kb) {
  const float SC = 0.18033688011112042f;  /* 0.125 * log2(e): folds 1/sqrt(d) and exp->exp2 */
  int idx = blockIdx.x * blockDim.x + threadIdx.x;
  int i  = idx & 31;
  int h  = (idx >> 5) & 15;
  int bl = idx >> 9;
  int l  = bl & (SEQ - 1);
  int b  = bl >> 11;
  float c = cs[l * 32 + i];
  float s = sn[l * 32 + i];
  size_t base = (size_t)bl * N3 + h * HDIM + 2 * i;
  uint32_t kp = *(const uint32_t*)(kqv + base);
  uint32_t qp = *(const uint32_t*)(kqv + base + DMODEL);
  float k1 = b2f((ushort)(kp & 0xffff)), k2 = b2f((ushort)(kp >> 16));
  float q1 = b2f((ushort)(qp & 0xffff)), q2 = b2f((ushort)(qp >> 16));
  float kr1 = k1 * c - k2 * s, kr2 = k1 * s + k2 * c;
  float qr1 = (q1 * c - q2 * s) * SC, qr2 = (q1 * s + q2 * c) * SC;
  size_t ob = ((size_t)(b * NHEADS + h) * SEQ + l) * HDIM + 2 * i;
  *(uint32_t*)(kb + ob) = (uint32_t)f2b(kr1) | ((uint32_t)f2b(kr2) << 16);
  *(uint32_t*)(qb + ob) = (uint32_t)f2b(qr1) | ((uint32_t)f2b(qr2) << 16);
}

/* ---------------- V transpose: kqv cols [2048,3072) -> Vt (b,h,64,L) bf16 ---------------- */
__global__ void vtrans_kernel(const ushort* __restrict__ kqv, ushort* __restrict__ vt) {
  __shared__ ushort tile[64][65];
  int bid = blockIdx.x;
  int lt = bid & 31, bh = bid >> 5;
  int b = bh >> 4, h = bh & 15;
  int tid = threadIdx.x;
  int r = tid >> 2, cq = tid & 3;
  size_t gbase = ((size_t)(b * SEQ + lt * 64 + r)) * N3 + 2 * DMODEL + h * HDIM + cq * 16;
#pragma unroll
  for (int j = 0; j < 16; ++j) tile[r][cq * 16 + j] = kqv[gbase + j];
  __syncthreads();
  int d = tid >> 2;
  size_t obase = ((size_t)(bh * HDIM + d)) * SEQ + lt * 64 + cq * 16;
#pragma unroll
  for (int j = 0; j < 16; ++j) vt[obase + j] = tile[cq * 16 + j][d];
}

/* ---------------- Flash attention partials: swapped-QK 16x16, split-KV,
   double-buffered global_load_lds staging (2-phase pipeline) ----------------
   R6's verified math, with all global K/V reads replaced by cooperative DMA
   staging into LDS: per kt, K-tile [64kv][64d] 8KB + V-tile [64d][64kv] 8KB,
   each via 16B global_load_lds (linear dest, source pre-swizzled slot^(row&7);
   ds_read applies the same XOR -> involution consistent both sides).
   STAGE(t+1) issued BEFORE compute(t); one __syncthreads per iter drains.
   LDS: 2*8K + 2*8K + 8K(P) = 40KB -> 4 blocks/CU. */
__global__ __launch_bounds__(256, 4)
void attn_part_kernel(const ushort* __restrict__ qb, const ushort* __restrict__ kb,
                      const ushort* __restrict__ vt,
                      ushort* __restrict__ po, float* __restrict__ pm, float* __restrict__ pl) {
  __shared__ __align__(16) ushort Kbuf[2][4096];   /* [kv 64][d 64] swizzled */
  __shared__ __align__(16) ushort Vbuf[2][4096];   /* [d 64][kv 64] swizzled */
  __shared__ __align__(16) ushort plds[4][1024];   /* per-wave P bounce */
  int bid = blockIdx.x;
  int bh = bid & 31;
  int slot = bid >> 5;
  int band = (slot < 8) ? 0 : (slot < 24) ? 1 : (slot < 48) ? 2 : 3;
  const int offb0 = (band == 0) ? 0 : (band == 1) ? 8 : (band == 2) ? 24 : 48;
  int s0i = slot - offb0;
  int qt = band * 8 + s0i / (band + 1);
  int c  = s0i % (band + 1);
  int kt0   = c * 8;
  int ktend = min(kt0 + 8, qt + 1);

  int wid = threadIdx.x >> 6, lane = threadIdx.x & 63;
  int l16 = lane & 15, lhi = lane >> 4;
  int r0 = qt * 64 + wid * 16;       /* wave's q-block; this lane's softmax q = r0 + l16 */

  const ushort* Q  = qb + (size_t)bh * SEQ * HDIM;
  const ushort* Kp = kb + (size_t)bh * SEQ * HDIM;
  const ushort* Vp = vt + (size_t)bh * HDIM * SEQ;

  bf16x8 qf[2];
#pragma unroll
  for (int kc = 0; kc < 2; ++kc)
    qf[kc] = *(const bf16x8*)(Q + (size_t)(r0 + l16) * HDIM + kc * 32 + lhi * 8);

  float mq = -3.0e38f, lsq = 0.0f;   /* state for q = r0 + l16 */
  f32x4 o[4] = {};                   /* o[f][r] = O[q=r0+lhi*4+r][d=f*16+l16], unnorm */

  char* pbase = (char*)&plds[wid][0];
  const int swz = (l16 & 7) << 4;    /* P-bounce XOR swizzle (verified R6) */

  /* stage K/V tile kt into buf: 512 chunks x 16B each; chunk ci -> row=ci>>3,
     src slot pre-swizzled so that LDS[row][slot] holds global[row][slot^(row&7)] */
  auto STAGE = [&](int buf, int kt) {
    ushort* kd = &Kbuf[buf][0];
    ushort* vd = &Vbuf[buf][0];
    const ushort* kg = Kp + (size_t)kt * 64 * HDIM;
    const ushort* vg = Vp + kt * 64;
#pragma unroll
    for (int it = 0; it < 2; ++it) {
      const int cb = it * 256 + wid * 64;          /* wave-uniform chunk base */
      const int ci = cb + lane;
      const int row = ci >> 3;
      const int sl  = (ci & 7) ^ (row & 7);
      __builtin_amdgcn_global_load_lds(
          (const __attribute__((address_space(1))) void*)(kg + row * HDIM + sl * 8),
          (__attribute__((address_space(3))) void*)(kd + cb * 8), 16, 0, 0);
      __builtin_amdgcn_global_load_lds(
          (const __attribute__((address_space(1))) void*)(vg + (size_t)row * SEQ + sl * 8),
          (__attribute__((address_space(3))) void*)(vd + cb * 8), 16, 0, 0);
    }
  };

  int cur = 0;
  STAGE(0, kt0);
  __syncthreads();

  for (int kt = kt0; kt < ktend; ++kt) {
    if (kt + 1 < ktend) STAGE(cur ^ 1, kt + 1);    /* issue next tile's DMA first */

    const char* kc_ = (const char*)&Kbuf[cur][0];
    const char* vc_ = (const char*)&Vbuf[cur][0];

    /* S^T = K * Q^T: s[n][r] = S[q=r0+l16][kv=kt*64+n*16+lhi*4+r] */
    f32x4 s[4];
#pragma unroll
    for (int n = 0; n < 4; ++n) {
      const int kvr = n * 16 + l16;
      bf16x8 kf0 = *(const bf16x8*)(kc_ + kvr*128 + ((lhi     ^ (kvr&7)) * 16));
      bf16x8 kf1 = *(const bf16x8*)(kc_ + kvr*128 + (((4+lhi) ^ (kvr&7)) * 16));
      f32x4 z = 0.0f;
      z = __builtin_amdgcn_mfma_f32_16x16x32_bf16(kf0, qf[0], z, 0, 0, 0);
      z = __builtin_amdgcn_mfma_f32_16x16x32_bf16(kf1, qf[1], z, 0, 0, 0);
      s[n] = z;
    }

    /* causal mask on diagonal tile: kv > q */
    if (kt == qt) {
#pragma unroll
      for (int n = 0; n < 4; ++n)
#pragma unroll
        for (int r = 0; r < 4; ++r)
          if (kt*64 + n*16 + lhi*4 + r > r0 + l16) s[n][r] = -3.0e38f;
    }

    /* row max: in-register tree + 2 shfl_xor (lanes sharing l16) */
    float t0 = fmaxf(fmaxf(s[0][0], s[0][1]), fmaxf(s[0][2], s[0][3]));
    float t1 = fmaxf(fmaxf(s[1][0], s[1][1]), fmaxf(s[1][2], s[1][3]));
    float t2 = fmaxf(fmaxf(s[2][0], s[2][1]), fmaxf(s[2][2], s[2][3]));
    float t3 = fmaxf(fmaxf(s[3][0], s[3][1]), fmaxf(s[3][2], s[3][3]));
    float pmx = fmaxf(fmaxf(t0, t1), fmaxf(t2, t3));
    pmx = fmaxf(pmx, __shfl_xor(pmx, 16));
    pmx = fmaxf(pmx, __shfl_xor(pmx, 32));

    /* rescale only when the running max grows (wave-uniform branch, exact) */
    if (!__all(pmx <= mq)) {
      float mn = fmaxf(mq, pmx);
      float alpha = exp2_hw(mq - mn);
      mq = mn;
      lsq *= alpha;
      float alphaT[4];
#pragma unroll
      for (int r = 0; r < 4; ++r)
        alphaT[r] = __shfl(alpha, lhi * 4 + r);
#pragma unroll
      for (int f = 0; f < 4; ++f)
#pragma unroll
        for (int r = 0; r < 4; ++r)
          o[f][r] *= alphaT[r];
    }

    /* p = exp2(s - m); sum via tree + 2 shfl_xor */
    float ps = 0.0f;
#pragma unroll
    for (int n = 0; n < 4; ++n)
#pragma unroll
      for (int r = 0; r < 4; ++r) {
        float p = exp2_hw(s[n][r] - mq);
        s[n][r] = p;
        ps += p;
      }
    ps += __shfl_xor(ps, 16);
    ps += __shfl_xor(ps, 32);
    lsq += ps;

    /* write P[q=l16][kv] to wave-private LDS (verified R6 path) */
#pragma unroll
    for (int n = 0; n < 4; ++n) {
      uint32_t w0 = (uint32_t)f2b(s[n][0]) | ((uint32_t)f2b(s[n][1]) << 16);
      uint32_t w1 = (uint32_t)f2b(s[n][2]) | ((uint32_t)f2b(s[n][3]) << 16);
      int kvloc = n*16 + lhi*4;
      *(uint32_t*)(pbase + ((l16*128 + kvloc*2) ^ swz))       = w0;
      *(uint32_t*)(pbase + ((l16*128 + (kvloc+2)*2) ^ swz))   = w1;
    }
    bf16x8 pa0 = *(const bf16x8*)(pbase + ((l16*128 + 0*64 + lhi*16) ^ swz));
    bf16x8 pa1 = *(const bf16x8*)(pbase + ((l16*128 + 1*64 + lhi*16) ^ swz));

    /* PV from staged V-tile: vf for d_row=f*16+l16, kv-slot cc*4+lhi (swizzled) */
#pragma unroll
    for (int f = 0; f < 4; ++f) {
      const int dr = f * 16 + l16;
      bf16x8 vf0 = *(const bf16x8*)(vc_ + dr*128 + ((lhi     ^ (dr&7)) * 16));
      bf16x8 vf1 = *(const bf16x8*)(vc_ + dr*128 + (((4+lhi) ^ (dr&7)) * 16));
      o[f] = __builtin_amdgcn_mfma_f32_16x16x32_bf16(pa0, vf0, o[f], 0, 0, 0);
      o[f] = __builtin_amdgcn_mfma_f32_16x16x32_bf16(pa1, vf1, o[f], 0, 0, 0);
    }

    __syncthreads();    /* drains DMA for tile kt+1; protects buf reuse */
    cur ^= 1;
  }

  /* store partials (layout verified R3/R6) */
  size_t pb = (size_t)bh * NSLOT + slot;
  if (lhi == 0) {
    pm[pb * 64 + wid * 16 + l16] = mq;
    pl[pb * 64 + wid * 16 + l16] = lsq;
  }
  int qlr = wid * 16 + lhi * 4;
#pragma unroll
  for (int r = 0; r < 4; ++r)
#pragma unroll
    for (int f = 0; f < 4; ++f)
      po[pb * 4096 + (size_t)(qlr + r) * 64 + f*16 + l16] = f2b(o[f][r]);
}

/* ---------------- Merge partials -> attn (b,L,h*d) bf16 ---------------- */
__global__ __launch_bounds__(256)
void attn_merge_kernel(const ushort* __restrict__ po, const float* __restrict__ pm,
                       const float* __restrict__ pl, ushort* __restrict__ attn) {
  int bid = blockIdx.x;            /* 1024: bh = bid&31, qt = bid>>5 */
  int bh = bid & 31, qt = bid >> 5;
  int band = qt >> 3;
  int nc = band + 1;
  int off = band * (band + 1) * 4 + (qt & 7) * (band + 1);
  size_t sbase = (size_t)bh * NSLOT + off;
  int t = threadIdx.x;
  int r = t >> 2, cg = t & 3;

  float mv[4], w[4];
  float M = -3.0e38f;
#pragma unroll
  for (int ci = 0; ci < 4; ++ci) {
    mv[ci] = (ci < nc) ? pm[(sbase + ci) * 64 + r] : -3.0e38f;
    M = fmaxf(M, mv[ci]);
  }
  float L = 0.0f;
#pragma unroll
  for (int ci = 0; ci < 4; ++ci) {
    w[ci] = (ci < nc) ? exp2f(mv[ci] - M) : 0.0f;
    if (ci < nc) L += w[ci] * pl[(sbase + ci) * 64 + r];
  }
  float acc[16] = {};
#pragma unroll
  for (int ci = 0; ci < 4; ++ci) {
    if (ci < nc) {
      const ushort* op = po + (sbase + ci) * 4096 + (size_t)r * 64 + cg * 16;
      uint4 v0 = *(const uint4*)op;
      uint4 v1 = *(const uint4*)(op + 8);
      const uint32_t uu[8] = {v0.x, v0.y, v0.z, v0.w, v1.x, v1.y, v1.z, v1.w};
#pragma unroll
      for (int j = 0; j < 8; ++j) {
        acc[2*j]   += w[ci] * b2f((ushort)(uu[j] & 0xffff));
        acc[2*j+1] += w[ci] * b2f((ushort)(uu[j] >> 16));
      }
    }
  }
  float invL = 1.0f / L;
  int b = bh >> 4, h = bh & 15;
  size_t ob = ((size_t)(b * SEQ + qt * 64 + r)) * DMODEL + h * 64 + cg * 16;
  uint32_t packed[8];
#pragma unroll
  for (int j = 0; j < 8; ++j)
    packed[j] = (uint32_t)f2b(acc[2*j] * invL) | ((uint32_t)f2b(acc[2*j+1] * invL) << 16);
  *(uint4*)(attn + ob)     = make_uint4(packed[0], packed[1], packed[2], packed[3]);
  *(uint4*)(attn + ob + 8) = make_uint4(packed[4], packed[5], packed[6], packed[7]);
}

extern "C" void kernel_launch(void* const* d_in, const int* in_sizes, int n_in,
                              void* d_out, int out_size, void* d_ws, size_t ws_size,
                              hipStream_t stream) {
  const float* x    = (const float*)d_in[0];
  const float* wkqv = (const float*)d_in[1];
  const float* wo   = (const float*)d_in[2];
  float* out = (float*)d_out;

  ushort* xb   = (ushort*)d_ws;                     /* 4096*1024 — reused as attn out */
  ushort* wkb  = xb  + (size_t)MROWS * DMODEL;      /* 3072*1024 */
  ushort* wob  = wkb + (size_t)N3 * DMODEL;         /* 1024*1024 */
  ushort* kqv  = wob + (size_t)DMODEL * DMODEL;     /* 4096*3072 — reused for partials */
  ushort* qb   = kqv + (size_t)MROWS * N3;          /* 4096*1024 */
  ushort* kb   = qb  + (size_t)MROWS * DMODEL;      /* 4096*1024 */
  ushort* vt   = kb  + (size_t)MROWS * DMODEL;      /* 4096*1024 */
  float*  cs   = (float*)(vt + (size_t)MROWS * DMODEL);
  float*  sn   = cs + SEQ * 32;
  ushort* attn = xb;  /* alias: xb dead after GEMM1 */

  /* partials alias kqv (dead after rope+vtrans) */
  ushort* po = kqv;
  float*  pmv = (float*)(kqv + (size_t)32 * NSLOT * 4096);
  float*  plv = pmv + (size_t)32 * NSLOT * 64;

  int nx = MROWS * DMODEL / 4, nw = N3 * DMODEL / 4, no = DMODEL * DMODEL / 4;
  f2b_kernel<<<nx / 256, 256, 0, stream>>>(x, xb, nx);
  f2b_kernel<<<nw / 256, 256, 0, stream>>>(wkqv, wkb, nw);
  f2b_kernel<<<no / 256, 256, 0, stream>>>(wo, wob, no);
  rope_table_kernel<<<SEQ * 32 / 256, 256, 0, stream>>>(cs, sn);

  gemm_bt<0><<<(MROWS/128) * (N3/128), 256, 0, stream>>>(xb, wkb, (void*)kqv, MROWS, N3, DMODEL);

  rope_kernel<<<(MROWS * NHEADS * 32) / 256, 256, 0, stream>>>(kqv, cs, sn, qb, kb);
  vtrans_kernel<<<BATCH * NHEADS * (SEQ / 64), 256, 0, stream>>>(kqv, vt);

  attn_part_kernel<<<32 * NSLOT, 256, 0, stream>>>(qb, kb, vt, po, pmv, plv);
  attn_merge_kernel<<<32 * 32, 256, 0, stream>>>(po, pmv, plv, attn);

  gemm_bt<1><<<(MROWS/128) * (DMODEL/128), 256, 0, stream>>>(attn, wob, (void*)out, MROWS, DMODEL, DMODEL);
}

// Round 8
// 134.820 us; speedup vs baseline: 1.7847x; 1.0686x over previous
//
#include <hip/hip_runtime.h>
#include <hip/hip_bf16.h>
#include <stdint.h>

#define BATCH 2
#define SEQ 2048
#define DMODEL 1024
#define NHEADS 16
#define HDIM 64
#define MROWS (BATCH*SEQ)   /* 4096 */
#define N3 (3*DMODEL)       /* 3072 */
#define NSLOT 80            /* chunk-slots per bh: sum over qt of ceil((qt+1)/8) */

typedef __attribute__((ext_vector_type(8))) __bf16 bf16x8;
typedef __attribute__((ext_vector_type(4))) float f32x4;

__device__ __forceinline__ ushort f2b(float f) {
  uint32_t u = __builtin_bit_cast(uint32_t, f);
  uint32_t r = (u + 0x7FFFu + ((u >> 16) & 1u)) >> 16;
  return (ushort)r;
}
__device__ __forceinline__ float b2f(ushort h) {
  return __builtin_bit_cast(float, (uint32_t)h << 16);
}
__device__ __forceinline__ float exp2_hw(float x) {
  float r;
  asm("v_exp_f32 %0, %1" : "=v"(r) : "v"(x));
  return r;
}
/* v_cvt_pk_bf16_f32: d.lo = bf16_rne(a), d.hi = bf16_rne(b) — 1 op replaces ~9 */
__device__ __forceinline__ uint32_t cvtpk(float a, float b) {
  uint32_t r;
  asm("v_cvt_pk_bf16_f32 %0, %1, %2" : "=v"(r) : "v"(a), "v"(b));
  return r;
}

/* ---------------- fused f32 -> bf16 convert for x, W_kqv, W_o (one launch) ---------------- */
__global__ void f2b3_kernel(const float* __restrict__ a, const float* __restrict__ b,
                            const float* __restrict__ c,
                            ushort* __restrict__ oa, ushort* __restrict__ ob,
                            ushort* __restrict__ oc, int na, int nb, int nc) {
  int i = blockIdx.x * blockDim.x + threadIdx.x;
  const float* src; ushort* dst; int off;
  if (i < na)           { src = a; dst = oa; off = i; }
  else if (i < na + nb) { src = b; dst = ob; off = i - na; }
  else if (i < na + nb + nc) { src = c; dst = oc; off = i - na - nb; }
  else return;
  float4 v = ((const float4*)src)[off];
  uint32_t lo = cvtpk(v.x, v.y), hi_ = cvtpk(v.z, v.w);
  ((uint2*)dst)[off] = make_uint2(lo, hi_);
}

/* ---------------- NT GEMM: C[M,N] = A[M,K] * Bw[N,K]^T  (m97 structure) ---------------- */
template<int OUTF>
__global__ __launch_bounds__(256)
void gemm_bt(const ushort* __restrict__ A, const ushort* __restrict__ Bw,
             void* __restrict__ Cv, int M, int N, int K) {
  __shared__ __align__(16) ushort As[128*32];
  __shared__ __align__(16) ushort Bs[128*32];
  const int tid  = threadIdx.x;
  const int wid  = tid >> 6;
  const int lane = tid & 63;
  const int wr   = wid >> 1, wc = wid & 1;
  const int l16  = lane & 15, lhi = lane >> 4;
  const int nb   = N >> 7;
  const int brow = (blockIdx.x / nb) << 7;
  const int bcol = (blockIdx.x % nb) << 7;

  f32x4 acc[4][4] = {};

  for (int k0 = 0; k0 < K; k0 += 32) {
    __syncthreads();
#pragma unroll
    for (int it = 0; it < 2; ++it) {
      const int cb    = (wid * 2 + it) * 64;
      const int chunk = cb + lane;
      const int r     = chunk >> 2;
      const int c8    = chunk & 3;
      const ushort* ga = A  + (size_t)(brow + r) * K + k0 + c8 * 8;
      const ushort* gb = Bw + (size_t)(bcol + r) * K + k0 + c8 * 8;
      __builtin_amdgcn_global_load_lds(
          (const __attribute__((address_space(1))) void*)ga,
          (__attribute__((address_space(3))) void*)(As + cb * 8), 16, 0, 0);
      __builtin_amdgcn_global_load_lds(
          (const __attribute__((address_space(1))) void*)gb,
          (__attribute__((address_space(3))) void*)(Bs + cb * 8), 16, 0, 0);
    }
    __syncthreads();

    bf16x8 af[4], bfr[4];
#pragma unroll
    for (int m = 0; m < 4; ++m)
      af[m] = *(const bf16x8*)(As + (wr*64 + m*16 + l16)*32 + lhi*8);
#pragma unroll
    for (int n = 0; n < 4; ++n)
      bfr[n] = *(const bf16x8*)(Bs + (wc*64 + n*16 + l16)*32 + lhi*8);
#pragma unroll
    for (int m = 0; m < 4; ++m)
#pragma unroll
      for (int n = 0; n < 4; ++n)
        acc[m][n] = __builtin_amdgcn_mfma_f32_16x16x32_bf16(af[m], bfr[n], acc[m][n], 0, 0, 0);
  }

#pragma unroll
  for (int m = 0; m < 4; ++m)
#pragma unroll
    for (int n = 0; n < 4; ++n)
#pragma unroll
      for (int r = 0; r < 4; ++r) {
        const int row = brow + wr*64 + m*16 + lhi*4 + r;
        const int col = bcol + wc*64 + n*16 + l16;
        if (OUTF) ((float*)Cv)[(size_t)row * N + col] = acc[m][n][r];
        else      ((ushort*)Cv)[(size_t)row * N + col] = f2b(acc[m][n][r]);
      }
}

/* ---------------- RoPE (table folded in): kqv(bf16) -> Qb (pre-scaled), Kb (b,h,L,64) ---------------- */
__global__ void rope_kernel(const ushort* __restrict__ kqv,
                            ushort* __restrict__ qb, ushort* __restrict__ kb) {
  const float SC = 0.18033688011112042f;  /* 0.125 * log2(e): folds 1/sqrt(d) and exp->exp2 */
  int idx = blockIdx.x * blockDim.x + threadIdx.x;
  int i  = idx & 31;
  int h  = (idx >> 5) & 15;
  int bl = idx >> 9;
  int l  = bl & (SEQ - 1);
  int b  = bl >> 11;
  /* inv = 10000^(-i/32) = exp2(-i * log2(10000)/32) */
  float inv = exp2f((float)i * -0.4152410118609203f);
  float ang = (float)l * inv;
  float s, c;
  sincosf(ang, &s, &c);
  size_t base = (size_t)bl * N3 + h * HDIM + 2 * i;
  uint32_t kp = *(const uint32_t*)(kqv + base);
  uint32_t qp = *(const uint32_t*)(kqv + base + DMODEL);
  float k1 = b2f((ushort)(kp & 0xffff)), k2 = b2f((ushort)(kp >> 16));
  float q1 = b2f((ushort)(qp & 0xffff)), q2 = b2f((ushort)(qp >> 16));
  float kr1 = k1 * c - k2 * s, kr2 = k1 * s + k2 * c;
  float qr1 = (q1 * c - q2 * s) * SC, qr2 = (q1 * s + q2 * c) * SC;
  size_t ob = ((size_t)(b * NHEADS + h) * SEQ + l) * HDIM + 2 * i;
  *(uint32_t*)(kb + ob) = cvtpk(kr1, kr2);
  *(uint32_t*)(qb + ob) = cvtpk(qr1, qr2);
}

/* ---------------- V transpose: kqv cols [2048,3072) -> Vt (b,h,64,L) bf16 ---------------- */
__global__ void vtrans_kernel(const ushort* __restrict__ kqv, ushort* __restrict__ vt) {
  __shared__ ushort tile[64][65];
  int bid = blockIdx.x;
  int lt = bid & 31, bh = bid >> 5;
  int b = bh >> 4, h = bh & 15;
  int tid = threadIdx.x;
  int r = tid >> 2, cq = tid & 3;
  size_t gbase = ((size_t)(b * SEQ + lt * 64 + r)) * N3 + 2 * DMODEL + h * HDIM + cq * 16;
#pragma unroll
  for (int j = 0; j < 16; ++j) tile[r][cq * 16 + j] = kqv[gbase + j];
  __syncthreads();
  int d = tid >> 2;
  size_t obase = ((size_t)(bh * HDIM + d)) * SEQ + lt * 64 + cq * 16;
#pragma unroll
  for (int j = 0; j < 16; ++j) vt[obase + j] = tile[cq * 16 + j][d];
}

/* ---------------- Flash attention partials: swapped-QK 16x16, split-KV,
   double-buffered global_load_lds staging (verified R7 structure).
   This round: P-pack via v_cvt_pk_bf16_f32 (8 ops replace ~72 scalar-VALU). ---------------- */
__global__ __launch_bounds__(256, 4)
void attn_part_kernel(const ushort* __restrict__ qb, const ushort* __restrict__ kb,
                      const ushort* __restrict__ vt,
                      ushort* __restrict__ po, float* __restrict__ pm, float* __restrict__ pl) {
  __shared__ __align__(16) ushort Kbuf[2][4096];   /* [kv 64][d 64] swizzled */
  __shared__ __align__(16) ushort Vbuf[2][4096];   /* [d 64][kv 64] swizzled */
  __shared__ __align__(16) ushort plds[4][1024];   /* per-wave P bounce */
  int bid = blockIdx.x;
  int bh = bid & 31;
  int slot = bid >> 5;
  int band = (slot < 8) ? 0 : (slot < 24) ? 1 : (slot < 48) ? 2 : 3;
  const int offb0 = (band == 0) ? 0 : (band == 1) ? 8 : (band == 2) ? 24 : 48;
  int s0i = slot - offb0;
  int qt = band * 8 + s0i / (band + 1);
  int c  = s0i % (band + 1);
  int kt0   = c * 8;
  int ktend = min(kt0 + 8, qt + 1);

  int wid = threadIdx.x >> 6, lane = threadIdx.x & 63;
  int l16 = lane & 15, lhi = lane >> 4;
  int r0 = qt * 64 + wid * 16;       /* wave's q-block; this lane's softmax q = r0 + l16 */

  const ushort* Q  = qb + (size_t)bh * SEQ * HDIM;
  const ushort* Kp = kb + (size_t)bh * SEQ * HDIM;
  const ushort* Vp = vt + (size_t)bh * HDIM * SEQ;

  bf16x8 qf[2];
#pragma unroll
  for (int kc = 0; kc < 2; ++kc)
    qf[kc] = *(const bf16x8*)(Q + (size_t)(r0 + l16) * HDIM + kc * 32 + lhi * 8);

  float mq = -3.0e38f, lsq = 0.0f;   /* state for q = r0 + l16 */
  f32x4 o[4] = {};                   /* o[f][r] = O[q=r0+lhi*4+r][d=f*16+l16], unnorm */

  char* pbase = (char*)&plds[wid][0];
  const int swz = (l16 & 7) << 4;    /* P-bounce XOR swizzle (verified R6/R7) */

  auto STAGE = [&](int buf, int kt) {
    ushort* kd = &Kbuf[buf][0];
    ushort* vd = &Vbuf[buf][0];
    const ushort* kg = Kp + (size_t)kt * 64 * HDIM;
    const ushort* vg = Vp + kt * 64;
#pragma unroll
    for (int it = 0; it < 2; ++it) {
      const int cb = it * 256 + wid * 64;          /* wave-uniform chunk base */
      const int ci = cb + lane;
      const int row = ci >> 3;
      const int sl  = (ci & 7) ^ (row & 7);
      __builtin_amdgcn_global_load_lds(
          (const __attribute__((address_space(1))) void*)(kg + row * HDIM + sl * 8),
          (__attribute__((address_space(3))) void*)(kd + cb * 8), 16, 0, 0);
      __builtin_amdgcn_global_load_lds(
          (const __attribute__((address_space(1))) void*)(vg + (size_t)row * SEQ + sl * 8),
          (__attribute__((address_space(3))) void*)(vd + cb * 8), 16, 0, 0);
    }
  };

  int cur = 0;
  STAGE(0, kt0);
  __syncthreads();

  for (int kt = kt0; kt < ktend; ++kt) {
    if (kt + 1 < ktend) STAGE(cur ^ 1, kt + 1);    /* issue next tile's DMA first */

    const char* kc_ = (const char*)&Kbuf[cur][0];
    const char* vc_ = (const char*)&Vbuf[cur][0];

    /* S^T = K * Q^T: s[n][r] = S[q=r0+l16][kv=kt*64+n*16+lhi*4+r] */
    f32x4 s[4];
#pragma unroll
    for (int n = 0; n < 4; ++n) {
      const int kvr = n * 16 + l16;
      bf16x8 kf0 = *(const bf16x8*)(kc_ + kvr*128 + ((lhi     ^ (kvr&7)) * 16));
      bf16x8 kf1 = *(const bf16x8*)(kc_ + kvr*128 + (((4+lhi) ^ (kvr&7)) * 16));
      f32x4 z = 0.0f;
      z = __builtin_amdgcn_mfma_f32_16x16x32_bf16(kf0, qf[0], z, 0, 0, 0);
      z = __builtin_amdgcn_mfma_f32_16x16x32_bf16(kf1, qf[1], z, 0, 0, 0);
      s[n] = z;
    }

    /* causal mask on diagonal tile: kv > q */
    if (kt == qt) {
#pragma unroll
      for (int n = 0; n < 4; ++n)
#pragma unroll
        for (int r = 0; r < 4; ++r)
          if (kt*64 + n*16 + lhi*4 + r > r0 + l16) s[n][r] = -3.0e38f;
    }

    /* row max: in-register tree + 2 shfl_xor (lanes sharing l16) */
    float t0 = fmaxf(fmaxf(s[0][0], s[0][1]), fmaxf(s[0][2], s[0][3]));
    float t1 = fmaxf(fmaxf(s[1][0], s[1][1]), fmaxf(s[1][2], s[1][3]));
    float t2 = fmaxf(fmaxf(s[2][0], s[2][1]), fmaxf(s[2][2], s[2][3]));
    float t3 = fmaxf(fmaxf(s[3][0], s[3][1]), fmaxf(s[3][2], s[3][3]));
    float pmx = fmaxf(fmaxf(t0, t1), fmaxf(t2, t3));
    pmx = fmaxf(pmx, __shfl_xor(pmx, 16));
    pmx = fmaxf(pmx, __shfl_xor(pmx, 32));

    /* rescale only when the running max grows (wave-uniform branch, exact) */
    if (!__all(pmx <= mq)) {
      float mn = fmaxf(mq, pmx);
      float alpha = exp2_hw(mq - mn);
      mq = mn;
      lsq *= alpha;
      float alphaT[4];
#pragma unroll
      for (int r = 0; r < 4; ++r)
        alphaT[r] = __shfl(alpha, lhi * 4 + r);
#pragma unroll
      for (int f = 0; f < 4; ++f)
#pragma unroll
        for (int r = 0; r < 4; ++r)
          o[f][r] *= alphaT[r];
    }

    /* p = exp2(s - m); sum via tree + 2 shfl_xor */
    float ps = 0.0f;
#pragma unroll
    for (int n = 0; n < 4; ++n)
#pragma unroll
      for (int r = 0; r < 4; ++r) {
        float p = exp2_hw(s[n][r] - mq);
        s[n][r] = p;
        ps += p;
      }
    ps += __shfl_xor(ps, 16);
    ps += __shfl_xor(ps, 32);
    lsq += ps;

    /* write P[q=l16][kv] to wave-private LDS — pack via v_cvt_pk_bf16_f32 */
#pragma unroll
    for (int n = 0; n < 4; ++n) {
      uint32_t w0 = cvtpk(s[n][0], s[n][1]);
      uint32_t w1 = cvtpk(s[n][2], s[n][3]);
      int kvloc = n*16 + lhi*4;
      *(uint32_t*)(pbase + ((l16*128 + kvloc*2) ^ swz))       = w0;
      *(uint32_t*)(pbase + ((l16*128 + (kvloc+2)*2) ^ swz))   = w1;
    }
    bf16x8 pa0 = *(const bf16x8*)(pbase + ((l16*128 + 0*64 + lhi*16) ^ swz));
    bf16x8 pa1 = *(const bf16x8*)(pbase + ((l16*128 + 1*64 + lhi*16) ^ swz));

    /* PV from staged V-tile */
#pragma unroll
    for (int f = 0; f < 4; ++f) {
      const int dr = f * 16 + l16;
      bf16x8 vf0 = *(const bf16x8*)(vc_ + dr*128 + ((lhi     ^ (dr&7)) * 16));
      bf16x8 vf1 = *(const bf16x8*)(vc_ + dr*128 + (((4+lhi) ^ (dr&7)) * 16));
      o[f] = __builtin_amdgcn_mfma_f32_16x16x32_bf16(pa0, vf0, o[f], 0, 0, 0);
      o[f] = __builtin_amdgcn_mfma_f32_16x16x32_bf16(pa1, vf1, o[f], 0, 0, 0);
    }

    __syncthreads();    /* drains DMA for tile kt+1; protects buf reuse */
    cur ^= 1;
  }

  /* store partials (layout verified R3/R6/R7) */
  size_t pb = (size_t)bh * NSLOT + slot;
  if (lhi == 0) {
    pm[pb * 64 + wid * 16 + l16] = mq;
    pl[pb * 64 + wid * 16 + l16] = lsq;
  }
  int qlr = wid * 16 + lhi * 4;
#pragma unroll
  for (int r = 0; r < 4; ++r)
#pragma unroll
    for (int f = 0; f < 4; ++f)
      po[pb * 4096 + (size_t)(qlr + r) * 64 + f*16 + l16] = f2b(o[f][r]);
}

/* ---------------- Merge partials -> attn (b,L,h*d) bf16 ---------------- */
__global__ __launch_bounds__(256)
void attn_merge_kernel(const ushort* __restrict__ po, const float* __restrict__ pm,
                       const float* __restrict__ pl, ushort* __restrict__ attn) {
  int bid = blockIdx.x;            /* 1024: bh = bid&31, qt = bid>>5 */
  int bh = bid & 31, qt = bid >> 5;
  int band = qt >> 3;
  int nc = band + 1;
  int off = band * (band + 1) * 4 + (qt & 7) * (band + 1);
  size_t sbase = (size_t)bh * NSLOT + off;
  int t = threadIdx.x;
  int r = t >> 2, cg = t & 3;

  float mv[4], w[4];
  float M = -3.0e38f;
#pragma unroll
  for (int ci = 0; ci < 4; ++ci) {
    mv[ci] = (ci < nc) ? pm[(sbase + ci) * 64 + r] : -3.0e38f;
    M = fmaxf(M, mv[ci]);
  }
  float L = 0.0f;
#pragma unroll
  for (int ci = 0; ci < 4; ++ci) {
    w[ci] = (ci < nc) ? exp2f(mv[ci] - M) : 0.0f;
    if (ci < nc) L += w[ci] * pl[(sbase + ci) * 64 + r];
  }
  float acc[16] = {};
#pragma unroll
  for (int ci = 0; ci < 4; ++ci) {
    if (ci < nc) {
      const ushort* op = po + (sbase + ci) * 4096 + (size_t)r * 64 + cg * 16;
      uint4 v0 = *(const uint4*)op;
      uint4 v1 = *(const uint4*)(op + 8);
      const uint32_t uu[8] = {v0.x, v0.y, v0.z, v0.w, v1.x, v1.y, v1.z, v1.w};
#pragma unroll
      for (int j = 0; j < 8; ++j) {
        acc[2*j]   += w[ci] * b2f((ushort)(uu[j] & 0xffff));
        acc[2*j+1] += w[ci] * b2f((ushort)(uu[j] >> 16));
      }
    }
  }
  float invL = 1.0f / L;
  int b = bh >> 4, h = bh & 15;
  size_t ob = ((size_t)(b * SEQ + qt * 64 + r)) * DMODEL + h * 64 + cg * 16;
  uint32_t packed[8];
#pragma unroll
  for (int j = 0; j < 8; ++j)
    packed[j] = cvtpk(acc[2*j] * invL, acc[2*j+1] * invL);
  *(uint4*)(attn + ob)     = make_uint4(packed[0], packed[1], packed[2], packed[3]);
  *(uint4*)(attn + ob + 8) = make_uint4(packed[4], packed[5], packed[6], packed[7]);
}

extern "C" void kernel_launch(void* const* d_in, const int* in_sizes, int n_in,
                              void* d_out, int out_size, void* d_ws, size_t ws_size,
                              hipStream_t stream) {
  const float* x    = (const float*)d_in[0];
  const float* wkqv = (const float*)d_in[1];
  const float* wo   = (const float*)d_in[2];
  float* out = (float*)d_out;

  ushort* xb   = (ushort*)d_ws;                     /* 4096*1024 — reused as attn out */
  ushort* wkb  = xb  + (size_t)MROWS * DMODEL;      /* 3072*1024 */
  ushort* wob  = wkb + (size_t)N3 * DMODEL;         /* 1024*1024 */
  ushort* kqv  = wob + (size_t)DMODEL * DMODEL;     /* 4096*3072 — reused for partials */
  ushort* qb   = kqv + (size_t)MROWS * N3;          /* 4096*1024 */
  ushort* kb   = qb  + (size_t)MROWS * DMODEL;      /* 4096*1024 */
  ushort* vt   = kb  + (size_t)MROWS * DMODEL;      /* 4096*1024 */
  ushort* attn = xb;  /* alias: xb dead after GEMM1 */

  /* partials alias kqv (dead after rope+vtrans) */
  ushort* po = kqv;
  float*  pmv = (float*)(kqv + (size_t)32 * NSLOT * 4096);
  float*  plv = pmv + (size_t)32 * NSLOT * 64;

  int nx = MROWS * DMODEL / 4, nw = N3 * DMODEL / 4, no = DMODEL * DMODEL / 4;
  f2b3_kernel<<<(nx + nw + no) / 256, 256, 0, stream>>>(x, wkqv, wo, xb, wkb, wob, nx, nw, no);

  gemm_bt<0><<<(MROWS/128) * (N3/128), 256, 0, stream>>>(xb, wkb, (void*)kqv, MROWS, N3, DMODEL);

  rope_kernel<<<(MROWS * NHEADS * 32) / 256, 256, 0, stream>>>(kqv, qb, kb);
  vtrans_kernel<<<BATCH * NHEADS * (SEQ / 64), 256, 0, stream>>>(kqv, vt);

  attn_part_kernel<<<32 * NSLOT, 256, 0, stream>>>(qb, kb, vt, po, pmv, plv);
  attn_merge_kernel<<<32 * 32, 256, 0, stream>>>(po, pmv, plv, attn);

  gemm_bt<1><<<(MROWS/128) * (DMODEL/128), 256, 0, stream>>>(attn, wob, (void*)out, MROWS, DMODEL, DMODEL);
}

// Round 9
// 126.604 us; speedup vs baseline: 1.9005x; 1.0649x over previous
//
#include <hip/hip_runtime.h>
#include <hip/hip_bf16.h>
#include <stdint.h>

#define BATCH 2
#define SEQ 2048
#define DMODEL 1024
#define NHEADS 16
#define HDIM 64
#define MROWS (BATCH*SEQ)   /* 4096 */
#define N3 (3*DMODEL)       /* 3072 */

typedef __attribute__((ext_vector_type(8))) __bf16 bf16x8;
typedef __attribute__((ext_vector_type(4))) float f32x4;

__device__ __forceinline__ ushort f2b(float f) {
  uint32_t u = __builtin_bit_cast(uint32_t, f);
  uint32_t r = (u + 0x7FFFu + ((u >> 16) & 1u)) >> 16;
  return (ushort)r;
}
__device__ __forceinline__ float b2f(ushort h) {
  return __builtin_bit_cast(float, (uint32_t)h << 16);
}
__device__ __forceinline__ float exp2_hw(float x) {
  float r;
  asm("v_exp_f32 %0, %1" : "=v"(r) : "v"(x));
  return r;
}
/* v_cvt_pk_bf16_f32: d.lo = bf16_rne(a), d.hi = bf16_rne(b) */
__device__ __forceinline__ uint32_t cvtpk(float a, float b) {
  uint32_t r;
  asm("v_cvt_pk_bf16_f32 %0, %1, %2" : "=v"(r) : "v"(a), "v"(b));
  return r;
}

/* ---------------- fused f32 -> bf16 convert for x, W_kqv, W_o (one launch) ---------------- */
__global__ void f2b3_kernel(const float* __restrict__ a, const float* __restrict__ b,
                            const float* __restrict__ c,
                            ushort* __restrict__ oa, ushort* __restrict__ ob,
                            ushort* __restrict__ oc, int na, int nb, int nc) {
  int i = blockIdx.x * blockDim.x + threadIdx.x;
  const float* src; ushort* dst; int off;
  if (i < na)           { src = a; dst = oa; off = i; }
  else if (i < na + nb) { src = b; dst = ob; off = i - na; }
  else if (i < na + nb + nc) { src = c; dst = oc; off = i - na - nb; }
  else return;
  float4 v = ((const float4*)src)[off];
  uint32_t lo = cvtpk(v.x, v.y), hi_ = cvtpk(v.z, v.w);
  ((uint2*)dst)[off] = make_uint2(lo, hi_);
}

/* ---------------- NT GEMM: C[M,N] = A[M,K] * Bw[N,K]^T  (m97 structure) ---------------- */
template<int OUTF>
__global__ __launch_bounds__(256)
void gemm_bt(const ushort* __restrict__ A, const ushort* __restrict__ Bw,
             void* __restrict__ Cv, int M, int N, int K) {
  __shared__ __align__(16) ushort As[128*32];
  __shared__ __align__(16) ushort Bs[128*32];
  const int tid  = threadIdx.x;
  const int wid  = tid >> 6;
  const int lane = tid & 63;
  const int wr   = wid >> 1, wc = wid & 1;
  const int l16  = lane & 15, lhi = lane >> 4;
  const int nb   = N >> 7;
  const int brow = (blockIdx.x / nb) << 7;
  const int bcol = (blockIdx.x % nb) << 7;

  f32x4 acc[4][4] = {};

  for (int k0 = 0; k0 < K; k0 += 32) {
    __syncthreads();
#pragma unroll
    for (int it = 0; it < 2; ++it) {
      const int cb    = (wid * 2 + it) * 64;
      const int chunk = cb + lane;
      const int r     = chunk >> 2;
      const int c8    = chunk & 3;
      const ushort* ga = A  + (size_t)(brow + r) * K + k0 + c8 * 8;
      const ushort* gb = Bw + (size_t)(bcol + r) * K + k0 + c8 * 8;
      __builtin_amdgcn_global_load_lds(
          (const __attribute__((address_space(1))) void*)ga,
          (__attribute__((address_space(3))) void*)(As + cb * 8), 16, 0, 0);
      __builtin_amdgcn_global_load_lds(
          (const __attribute__((address_space(1))) void*)gb,
          (__attribute__((address_space(3))) void*)(Bs + cb * 8), 16, 0, 0);
    }
    __syncthreads();

    bf16x8 af[4], bfr[4];
#pragma unroll
    for (int m = 0; m < 4; ++m)
      af[m] = *(const bf16x8*)(As + (wr*64 + m*16 + l16)*32 + lhi*8);
#pragma unroll
    for (int n = 0; n < 4; ++n)
      bfr[n] = *(const bf16x8*)(Bs + (wc*64 + n*16 + l16)*32 + lhi*8);
#pragma unroll
    for (int m = 0; m < 4; ++m)
#pragma unroll
      for (int n = 0; n < 4; ++n)
        acc[m][n] = __builtin_amdgcn_mfma_f32_16x16x32_bf16(af[m], bfr[n], acc[m][n], 0, 0, 0);
  }

#pragma unroll
  for (int m = 0; m < 4; ++m)
#pragma unroll
    for (int n = 0; n < 4; ++n)
#pragma unroll
      for (int r = 0; r < 4; ++r) {
        const int row = brow + wr*64 + m*16 + lhi*4 + r;
        const int col = bcol + wc*64 + n*16 + l16;
        if (OUTF) ((float*)Cv)[(size_t)row * N + col] = acc[m][n][r];
        else      ((ushort*)Cv)[(size_t)row * N + col] = f2b(acc[m][n][r]);
      }
}

/* ---------------- prep: fused V-transpose (blocks 0..1023) + RoPE (blocks 1024..9215) ---------------- */
__global__ __launch_bounds__(256)
void prep_kernel(const ushort* __restrict__ kqv,
                 ushort* __restrict__ qb, ushort* __restrict__ kb, ushort* __restrict__ vt) {
  __shared__ ushort tile[64][65];
  if (blockIdx.x < 1024) {
    /* V transpose: kqv cols [2048,3072) -> Vt (b,h,64,L) */
    int bid = blockIdx.x;
    int lt = bid & 31, bh = bid >> 5;
    int b = bh >> 4, h = bh & 15;
    int tid = threadIdx.x;
    int r = tid >> 2, cq = tid & 3;
    size_t gbase = ((size_t)(b * SEQ + lt * 64 + r)) * N3 + 2 * DMODEL + h * HDIM + cq * 16;
#pragma unroll
    for (int j = 0; j < 16; ++j) tile[r][cq * 16 + j] = kqv[gbase + j];
    __syncthreads();
    int d = tid >> 2;
    size_t obase = ((size_t)(bh * HDIM + d)) * SEQ + lt * 64 + cq * 16;
#pragma unroll
    for (int j = 0; j < 16; ++j) vt[obase + j] = tile[cq * 16 + j][d];
  } else {
    /* RoPE: kqv -> Qb (pre-scaled by 0.125*log2e), Kb (b,h,L,64) */
    const float SC = 0.18033688011112042f;
    int idx = (blockIdx.x - 1024) * 256 + threadIdx.x;
    int i  = idx & 31;
    int h  = (idx >> 5) & 15;
    int bl = idx >> 9;
    int l  = bl & (SEQ - 1);
    int b  = bl >> 11;
    float inv = exp2f((float)i * -0.4152410118609203f);  /* 10000^(-i/32) */
    float ang = (float)l * inv;
    float s, c;
    sincosf(ang, &s, &c);
    size_t base = (size_t)bl * N3 + h * HDIM + 2 * i;
    uint32_t kp = *(const uint32_t*)(kqv + base);
    uint32_t qp = *(const uint32_t*)(kqv + base + DMODEL);
    float k1 = b2f((ushort)(kp & 0xffff)), k2 = b2f((ushort)(kp >> 16));
    float q1 = b2f((ushort)(qp & 0xffff)), q2 = b2f((ushort)(qp >> 16));
    float kr1 = k1 * c - k2 * s, kr2 = k1 * s + k2 * c;
    float qr1 = (q1 * c - q2 * s) * SC, qr2 = (q1 * s + q2 * c) * SC;
    size_t ob = ((size_t)(b * NHEADS + h) * SEQ + l) * HDIM + 2 * i;
    *(uint32_t*)(kb + ob) = cvtpk(kr1, kr2);
    *(uint32_t*)(qb + ob) = cvtpk(qr1, qr2);
  }
}

/* ---------------- Flash attention, folded causal triangle ----------------
   Block = (bh, pair p): handles q-tiles qtA=p and qtB=31-p with ONE K/V stream:
   stage kt=0..qtB once; update B always, A while kt<=qtA. Every block = exactly
   33 compute-units -> uniform makespan, no partials, no merge, no dispatch-order
   assumptions. Inner math/LDS paths verbatim R8 (verified). Grid 512, 4 waves. */
__global__ __launch_bounds__(256, 2)
void attn_kernel(const ushort* __restrict__ qb, const ushort* __restrict__ kb,
                 const ushort* __restrict__ vt, ushort* __restrict__ ao) {
  __shared__ __align__(16) ushort Kbuf[2][4096];   /* [kv 64][d 64] swizzled */
  __shared__ __align__(16) ushort Vbuf[2][4096];   /* [d 64][kv 64] swizzled */
  __shared__ __align__(16) ushort plds[4][1024];   /* per-wave P bounce */
  const int bid = blockIdx.x;
  const int bh = bid & 31;
  const int p  = bid >> 5;           /* 0..15 */
  const int qtA = p, qtB = 31 - p;   /* qtB >= qtA */

  const int wid = threadIdx.x >> 6, lane = threadIdx.x & 63;
  const int l16 = lane & 15, lhi = lane >> 4;
  const int r0A = qtA * 64 + wid * 16;
  const int r0B = qtB * 64 + wid * 16;

  const ushort* Q  = qb + (size_t)bh * SEQ * HDIM;
  const ushort* Kp = kb + (size_t)bh * SEQ * HDIM;
  const ushort* Vp = vt + (size_t)bh * HDIM * SEQ;

  bf16x8 qfA[2], qfB[2];
#pragma unroll
  for (int kc = 0; kc < 2; ++kc) {
    qfA[kc] = *(const bf16x8*)(Q + (size_t)(r0A + l16) * HDIM + kc * 32 + lhi * 8);
    qfB[kc] = *(const bf16x8*)(Q + (size_t)(r0B + l16) * HDIM + kc * 32 + lhi * 8);
  }

  float mqA = -3.0e38f, lsA = 0.0f, mqB = -3.0e38f, lsB = 0.0f;
  f32x4 oA[4] = {}, oB[4] = {};

  char* pbase = (char*)&plds[wid][0];
  const int swz = (l16 & 7) << 4;

  auto STAGE = [&](int buf, int kt) {
    ushort* kd = &Kbuf[buf][0];
    ushort* vd = &Vbuf[buf][0];
    const ushort* kg = Kp + (size_t)kt * 64 * HDIM;
    const ushort* vg = Vp + kt * 64;
#pragma unroll
    for (int it = 0; it < 2; ++it) {
      const int cb = it * 256 + wid * 64;
      const int ci = cb + lane;
      const int row = ci >> 3;
      const int sl  = (ci & 7) ^ (row & 7);
      __builtin_amdgcn_global_load_lds(
          (const __attribute__((address_space(1))) void*)(kg + row * HDIM + sl * 8),
          (__attribute__((address_space(3))) void*)(kd + cb * 8), 16, 0, 0);
      __builtin_amdgcn_global_load_lds(
          (const __attribute__((address_space(1))) void*)(vg + (size_t)row * SEQ + sl * 8),
          (__attribute__((address_space(3))) void*)(vd + cb * 8), 16, 0, 0);
    }
  };

  /* one QK->softmax->PV update for q-tile (r0,qt) against staged tile kt (verbatim R8) */
  auto BODY = [&](const char* kc_, const char* vc_, bf16x8 (&qf)[2],
                  float& mq, float& lsq, f32x4 (&o)[4], int r0, int qt, int kt) {
    f32x4 s[4];
#pragma unroll
    for (int n = 0; n < 4; ++n) {
      const int kvr = n * 16 + l16;
      bf16x8 kf0 = *(const bf16x8*)(kc_ + kvr*128 + ((lhi     ^ (kvr&7)) * 16));
      bf16x8 kf1 = *(const bf16x8*)(kc_ + kvr*128 + (((4+lhi) ^ (kvr&7)) * 16));
      f32x4 z = 0.0f;
      z = __builtin_amdgcn_mfma_f32_16x16x32_bf16(kf0, qf[0], z, 0, 0, 0);
      z = __builtin_amdgcn_mfma_f32_16x16x32_bf16(kf1, qf[1], z, 0, 0, 0);
      s[n] = z;
    }
    if (kt == qt) {
#pragma unroll
      for (int n = 0; n < 4; ++n)
#pragma unroll
        for (int r = 0; r < 4; ++r)
          if (kt*64 + n*16 + lhi*4 + r > r0 + l16) s[n][r] = -3.0e38f;
    }
    float t0 = fmaxf(fmaxf(s[0][0], s[0][1]), fmaxf(s[0][2], s[0][3]));
    float t1 = fmaxf(fmaxf(s[1][0], s[1][1]), fmaxf(s[1][2], s[1][3]));
    float t2 = fmaxf(fmaxf(s[2][0], s[2][1]), fmaxf(s[2][2], s[2][3]));
    float t3 = fmaxf(fmaxf(s[3][0], s[3][1]), fmaxf(s[3][2], s[3][3]));
    float pmx = fmaxf(fmaxf(t0, t1), fmaxf(t2, t3));
    pmx = fmaxf(pmx, __shfl_xor(pmx, 16));
    pmx = fmaxf(pmx, __shfl_xor(pmx, 32));

    if (!__all(pmx <= mq)) {
      float mn = fmaxf(mq, pmx);
      float alpha = exp2_hw(mq - mn);
      mq = mn;
      lsq *= alpha;
      float alphaT[4];
#pragma unroll
      for (int r = 0; r < 4; ++r)
        alphaT[r] = __shfl(alpha, lhi * 4 + r);
#pragma unroll
      for (int f = 0; f < 4; ++f)
#pragma unroll
        for (int r = 0; r < 4; ++r)
          o[f][r] *= alphaT[r];
    }

    float ps = 0.0f;
#pragma unroll
    for (int n = 0; n < 4; ++n)
#pragma unroll
      for (int r = 0; r < 4; ++r) {
        float pv = exp2_hw(s[n][r] - mq);
        s[n][r] = pv;
        ps += pv;
      }
    ps += __shfl_xor(ps, 16);
    ps += __shfl_xor(ps, 32);
    lsq += ps;

#pragma unroll
    for (int n = 0; n < 4; ++n) {
      uint32_t w0 = cvtpk(s[n][0], s[n][1]);
      uint32_t w1 = cvtpk(s[n][2], s[n][3]);
      int kvloc = n*16 + lhi*4;
      *(uint32_t*)(pbase + ((l16*128 + kvloc*2) ^ swz))       = w0;
      *(uint32_t*)(pbase + ((l16*128 + (kvloc+2)*2) ^ swz))   = w1;
    }
    bf16x8 pa0 = *(const bf16x8*)(pbase + ((l16*128 + 0*64 + lhi*16) ^ swz));
    bf16x8 pa1 = *(const bf16x8*)(pbase + ((l16*128 + 1*64 + lhi*16) ^ swz));

#pragma unroll
    for (int f = 0; f < 4; ++f) {
      const int dr = f * 16 + l16;
      bf16x8 vf0 = *(const bf16x8*)(vc_ + dr*128 + ((lhi     ^ (dr&7)) * 16));
      bf16x8 vf1 = *(const bf16x8*)(vc_ + dr*128 + (((4+lhi) ^ (dr&7)) * 16));
      o[f] = __builtin_amdgcn_mfma_f32_16x16x32_bf16(pa0, vf0, o[f], 0, 0, 0);
      o[f] = __builtin_amdgcn_mfma_f32_16x16x32_bf16(pa1, vf1, o[f], 0, 0, 0);
    }
  };

  int cur = 0;
  STAGE(0, 0);
  __syncthreads();

  for (int kt = 0; kt <= qtB; ++kt) {
    if (kt < qtB) STAGE(cur ^ 1, kt + 1);          /* issue next tile's DMA first */
    const char* kc_ = (const char*)&Kbuf[cur][0];
    const char* vc_ = (const char*)&Vbuf[cur][0];
    BODY(kc_, vc_, qfB, mqB, lsB, oB, r0B, qtB, kt);
    if (kt <= qtA)
      BODY(kc_, vc_, qfA, mqA, lsA, oA, r0A, qtA, kt);
    __syncthreads();                               /* drains DMA; protects buf reuse */
    cur ^= 1;
  }

  /* epilogue: direct normalized store (invT via the verified alphaT-shfl pattern) */
  const int b = bh >> 4, h = bh & 15;
  float invA = 1.0f / lsA, invB = 1.0f / lsB;
#pragma unroll
  for (int r = 0; r < 4; ++r) {
    float wA = __shfl(invA, lhi * 4 + r);
    float wB = __shfl(invB, lhi * 4 + r);
    size_t baseA = ((size_t)(b * SEQ + r0A + lhi*4 + r)) * DMODEL + h * HDIM + l16;
    size_t baseB = ((size_t)(b * SEQ + r0B + lhi*4 + r)) * DMODEL + h * HDIM + l16;
#pragma unroll
    for (int f = 0; f < 4; ++f) {
      ao[baseA + f*16] = f2b(oA[f][r] * wA);
      ao[baseB + f*16] = f2b(oB[f][r] * wB);
    }
  }
}

extern "C" void kernel_launch(void* const* d_in, const int* in_sizes, int n_in,
                              void* d_out, int out_size, void* d_ws, size_t ws_size,
                              hipStream_t stream) {
  const float* x    = (const float*)d_in[0];
  const float* wkqv = (const float*)d_in[1];
  const float* wo   = (const float*)d_in[2];
  float* out = (float*)d_out;

  ushort* xb   = (ushort*)d_ws;                     /* 4096*1024 — reused as attn out */
  ushort* wkb  = xb  + (size_t)MROWS * DMODEL;      /* 3072*1024 */
  ushort* wob  = wkb + (size_t)N3 * DMODEL;         /* 1024*1024 */
  ushort* kqv  = wob + (size_t)DMODEL * DMODEL;     /* 4096*3072 */
  ushort* qb   = kqv + (size_t)MROWS * N3;          /* 4096*1024 */
  ushort* kb   = qb  + (size_t)MROWS * DMODEL;      /* 4096*1024 */
  ushort* vt   = kb  + (size_t)MROWS * DMODEL;      /* 4096*1024 */
  ushort* attn = xb;  /* alias: xb dead after GEMM1 */

  int nx = MROWS * DMODEL / 4, nw = N3 * DMODEL / 4, no = DMODEL * DMODEL / 4;
  f2b3_kernel<<<(nx + nw + no) / 256, 256, 0, stream>>>(x, wkqv, wo, xb, wkb, wob, nx, nw, no);

  gemm_bt<0><<<(MROWS/128) * (N3/128), 256, 0, stream>>>(xb, wkb, (void*)kqv, MROWS, N3, DMODEL);

  prep_kernel<<<1024 + (MROWS * NHEADS * 32) / 256, 256, 0, stream>>>(kqv, qb, kb, vt);

  attn_kernel<<<512, 256, 0, stream>>>(qb, kb, vt, attn);

  gemm_bt<1><<<(MROWS/128) * (DMODEL/128), 256, 0, stream>>>(attn, wob, (void*)out, MROWS, DMODEL, DMODEL);
}